// Round 18
// baseline (622.200 us; speedup 1.0000x reference)
//
#include <hip/hip_runtime.h>

// Problem constants
#define EE 8
#define BB 1024
#define DD 8192
#define HH 512
#define ZZ 128

typedef __attribute__((ext_vector_type(8))) short bf16x8;
typedef __attribute__((ext_vector_type(4))) float f32x4;
typedef __attribute__((address_space(1))) unsigned int u32g;
typedef __attribute__((address_space(3))) unsigned int u32l;

#define DEVI __device__ __forceinline__

DEVI float4 ld4(const float* p) { return *(const float4*)p; }

// RNE float -> bf16 bits
DEVI unsigned f2bf_u(float x) {
  unsigned u = __builtin_bit_cast(unsigned, x);
  return (u + 0x7FFFu + ((u >> 16) & 1u)) >> 16;
}
DEVI float bfu2f(unsigned h) { return __builtin_bit_cast(float, h << 16); }
DEVI float bf2f(short s) {
  return __builtin_bit_cast(float, ((unsigned)(unsigned short)s) << 16);
}
DEVI void split2(float x, short& hi, short& lo) {
  unsigned h = f2bf_u(x);
  hi = (short)h;
  lo = (short)f2bf_u(x - bfu2f(h));
}

// Direct global->LDS async copy, 16B per lane. LDS dest is wave-uniform
// base + lane*16 (linear); HW appends lane*16.
DEVI void gload16(const void* g, void* l) {
  __builtin_amdgcn_global_load_lds((const u32g*)g, (u32l*)l, 16, 0, 0);
}

// Pipeline fence: my loads drained (vmcnt 0) -> all waves here (raw barrier).
DEVI void pipe_fence() {
  __builtin_amdgcn_sched_barrier(0);
  asm volatile("s_waitcnt vmcnt(0)" ::: "memory");
  __builtin_amdgcn_s_barrier();
  __builtin_amdgcn_sched_barrier(0);
}

// Counted fences for the 4-buffer depth-3 pipeline (4 gloads per stage/wave):
// vmcnt(8): newest 2 stages may fly (stage c complete when c+1,c+2 in flight).
DEVI void fence_cnt8() {
  __builtin_amdgcn_sched_barrier(0);
  asm volatile("s_waitcnt vmcnt(8)" ::: "memory");
  __builtin_amdgcn_s_barrier();
  __builtin_amdgcn_sched_barrier(0);
}
// vmcnt(4): newest 1 stage may fly (tail peel).
DEVI void fence_cnt4() {
  __builtin_amdgcn_sched_barrier(0);
  asm volatile("s_waitcnt vmcnt(4)" ::: "memory");
  __builtin_amdgcn_s_barrier();
  __builtin_amdgcn_sched_barrier(0);
}

// ---- BK=64 staging (XOR-swizzled source).
template <int ROWS, int WAVES>
DEVI void stageG(const short* src, int Kb, short* lds, int w, int laneoff) {
  const char* p = (const char*)src + laneoff;
  char* l = (char*)lds + w * 1024;
#pragma unroll
  for (int r = 0; r < ROWS / (WAVES * 8); ++r)
    gload16(p + (size_t)r * (WAVES * 8) * Kb, l + r * (WAVES * 1024));
}

// ---- BK=32 staging (slot-swizzled source; conflict-free, r12-verified).
template <int ROWS, int WAVES>
DEVI void stage32(const short* src, int Kb, short* lds, int w, int laneoff32) {
  const char* p = (const char*)src + laneoff32;
  char* l = (char*)lds + w * 1024;
#pragma unroll
  for (int r = 0; r < ROWS / (WAVES * 16); ++r)
    gload16(p + (size_t)r * (WAVES * 16) * Kb, l + r * (WAVES * 1024));
}

// One K=64 chunk (swizzled BK=64 layout).
template <int NPASS, int NF>
DEVI void mma_chunk(const char* Ah, const char* Al, const char* Bh, const char* Bl,
                    int abase, int bbase, f32x4 acc[4][NF]) {
#pragma unroll
  for (int kk = 0; kk < 2; ++kk) {
    const int kx = kk * 64;
    bf16x8 ah[4], al[4], bh[NF], bl[NF];
#pragma unroll
    for (int m = 0; m < 4; ++m) {
      ah[m] = *(const bf16x8*)(Ah + ((abase + m * 2048) ^ kx));
      if (NPASS == 3) al[m] = *(const bf16x8*)(Al + ((abase + m * 2048) ^ kx));
    }
#pragma unroll
    for (int n = 0; n < NF; ++n) {
      bh[n] = *(const bf16x8*)(Bh + ((bbase + n * 2048) ^ kx));
      if (NPASS == 3) bl[n] = *(const bf16x8*)(Bl + ((bbase + n * 2048) ^ kx));
    }
#pragma unroll
    for (int m = 0; m < 4; ++m)
#pragma unroll
      for (int n = 0; n < NF; ++n) {
        acc[m][n] = __builtin_amdgcn_mfma_f32_16x16x32_bf16(ah[m], bh[n], acc[m][n], 0, 0, 0);
        if (NPASS == 3) {
          acc[m][n] = __builtin_amdgcn_mfma_f32_16x16x32_bf16(ah[m], bl[n], acc[m][n], 0, 0, 0);
          acc[m][n] = __builtin_amdgcn_mfma_f32_16x16x32_bf16(al[m], bh[n], acc[m][n], 0, 0, 0);
        }
      }
  }
}

// One K=32 chunk, BK=32 swizzled layout.
template <int NM, int NF>
DEVI void mma32(const char* A, const char* B, int abase, int bbase,
                f32x4 acc[NM][NF]) {
  bf16x8 ah[NM], bh[NF];
#pragma unroll
  for (int m = 0; m < NM; ++m) ah[m] = *(const bf16x8*)(A + abase + m * 1024);
#pragma unroll
  for (int n = 0; n < NF; ++n) bh[n] = *(const bf16x8*)(B + bbase + n * 1024);
#pragma unroll
  for (int m = 0; m < NM; ++m)
#pragma unroll
    for (int n = 0; n < NF; ++n)
      acc[m][n] = __builtin_amdgcn_mfma_f32_16x16x32_bf16(ah[m], bh[n], acc[m][n], 0, 0, 0);
}

// ---------------------------------------------------------------------------
// 4-wave GEMM (128 x NF*32 tile), single-buffer 2-barrier loop.
// ---------------------------------------------------------------------------
template <int NPASS, int NF, bool RELU, int OUT>
__global__ __launch_bounds__(256, (NPASS == 3 ? 2 : 3)) void gemm_k(
    const short* __restrict__ Ahg, const short* __restrict__ Alg,
    const short* __restrict__ Bhg, const short* __restrict__ Blg,
    const float* __restrict__ bias,
    float* __restrict__ Yf, short* __restrict__ Yh, short* __restrict__ Yl,
    int M, int N, int K, int APE, const int* __restrict__ cntPtr, int mSkip) {
  constexpr int BN = NF * 32;
  __shared__ short sA[(NPASS == 3 ? 2 : 1) * 128 * 64];
  __shared__ short sB[(NPASS == 3 ? 2 : 1) * BN * 64];
  const int e = blockIdx.z;
  const int m0 = blockIdx.y * 128, n0 = blockIdx.x * BN;
  if (m0 < mSkip) return;
  if (cntPtr) {
    if (m0 >= ((cntPtr[0] + 127) & ~127)) return;
  }
  const size_t eA = APE ? (size_t)e * M * K : 0;
  const short* Ae = Ahg + eA + (size_t)m0 * K;
  const short* Ale = (NPASS == 3) ? (Alg + eA + (size_t)m0 * K) : nullptr;
  const short* Be = Bhg + ((size_t)e * N + n0) * K;
  const short* Ble = (NPASS == 3) ? (Blg + ((size_t)e * N + n0) * K) : nullptr;

  const int t = threadIdx.x, w = t >> 6, lane = t & 63;
  const int wm = w >> 1, wn = w & 1;
  const int Kb = K * 2;
  const int laneoff = (w * 8 + (lane >> 3)) * Kb + (((lane & 7) ^ ((lane >> 3) & 7)) << 4);
  const int r16 = lane & 15, g = lane >> 4;
  const int c0 = ((g ^ (r16 & 7)) << 4);
  const int abase = (wm * 64 + r16) * 128 + c0;
  const int bbase = (wn * (NF * 16) + r16) * 128 + c0;

  f32x4 acc[4][NF];
#pragma unroll
  for (int m = 0; m < 4; ++m)
#pragma unroll
    for (int n = 0; n < NF; ++n) acc[m][n] = (f32x4){0.f, 0.f, 0.f, 0.f};

  for (int k0 = 0; k0 < K; k0 += 64) {
    stageG<128, 4>(Ae + k0, Kb, sA, w, laneoff);
    if (NPASS == 3) stageG<128, 4>(Ale + k0, Kb, sA + 128 * 64, w, laneoff);
    stageG<BN, 4>(Be + k0, Kb, sB, w, laneoff);
    if (NPASS == 3) stageG<BN, 4>(Ble + k0, Kb, sB + BN * 64, w, laneoff);
    __syncthreads();
    mma_chunk<NPASS, NF>((const char*)sA, (const char*)(sA + 128 * 64),
                         (const char*)sB, (const char*)(sB + BN * 64), abase, bbase, acc);
    __syncthreads();
  }

  const int col0 = n0 + wn * (NF * 16);
#pragma unroll
  for (int n = 0; n < NF; ++n) {
    const int cn = col0 + n * 16 + r16;
    const float bv = bias[(size_t)e * N + cn];
#pragma unroll
    for (int m = 0; m < 4; ++m)
#pragma unroll
      for (int r = 0; r < 4; ++r) {
        const int row = m0 + wm * 64 + m * 16 + g * 4 + r;
        float v = acc[m][n][r] + bv;
        if (RELU) v = fmaxf(v, 0.f);
        const size_t o = ((size_t)e * M + row) * N + cn;
        if (OUT == 0) {
          Yf[o] = v;
        } else {
          unsigned hb = f2bf_u(v);
          Yh[o] = (short)hb;
          if (NPASS == 3) Yl[o] = (short)f2bf_u(v - bfu2f(hb));
        }
      }
  }
}

// ---------------------------------------------------------------------------
// MAIN enc1 split-K, KS=2, BK=64 single-buffer, 128x128 tile (r13-proven).
// Grid 512 blocks: e = raw&7 (XCD owns one expert's B panel), m innermost.
// ---------------------------------------------------------------------------
__global__ __launch_bounds__(256, 4) void enc1_mainsplit_k(
    const short* __restrict__ Xhg, const short* __restrict__ Bhg,
    float* __restrict__ EncP) {
  __shared__ short sA[128 * 64];
  __shared__ short sB[128 * 64];
  const int raw = blockIdx.x;
  const int e = raw & 7;
  const int q = raw >> 3;          // [0,64)
  const int m0 = (q & 7) * 128;    // m innermost: B-slice shared by 8 adjacent
  const int ks = (q >> 3) & 1;
  const int n0 = (q >> 4) * 128;   // 4 n-blocks of 128
  const int Kb = DD * 2;
  const short* Ae = Xhg + (size_t)m0 * DD;
  const short* Be = Bhg + ((size_t)e * HH + n0) * DD;

  const int t = threadIdx.x, w = t >> 6, lane = t & 63;
  const int wm = w >> 1, wn = w & 1;
  const int laneoff = (w * 8 + (lane >> 3)) * Kb + (((lane & 7) ^ ((lane >> 3) & 7)) << 4);
  const int r16 = lane & 15, g = lane >> 4;
  const int c0 = ((g ^ (r16 & 7)) << 4);
  const int abase = (wm * 64 + r16) * 128 + c0;
  const int bbase = (wn * 64 + r16) * 128 + c0;

  f32x4 acc[4][4];
#pragma unroll
  for (int m = 0; m < 4; ++m)
#pragma unroll
    for (int n = 0; n < 4; ++n) acc[m][n] = (f32x4){0.f, 0.f, 0.f, 0.f};

  const int kbeg = ks * 4096, kend = kbeg + 4096;
  for (int k0 = kbeg; k0 < kend; k0 += 64) {
    stageG<128, 4>(Ae + k0, Kb, sA, w, laneoff);
    stageG<128, 4>(Be + k0, Kb, sB, w, laneoff);
    __syncthreads();
    mma_chunk<1, 4>((const char*)sA, nullptr, (const char*)sB, nullptr,
                    abase, bbase, acc);
    __syncthreads();
  }

#pragma unroll
  for (int n = 0; n < 4; ++n) {
    const int cn = n0 + wn * 64 + n * 16 + r16;
#pragma unroll
    for (int m = 0; m < 4; ++m)
#pragma unroll
      for (int r = 0; r < 4; ++r) {
        const int row = m0 + wm * 64 + m * 16 + g * 4 + r;
        EncP[(((size_t)ks * EE + e) * BB + row) * HH + cn] = acc[m][n][r];
      }
  }
}

// Sum KS=2 partials + bias + relu -> bf16 Hh. 2048 blocks x 256 thr, 8 elem/thr.
__global__ void fuse_enc1main_k(const float* __restrict__ EncP,
                                const float* __restrict__ enc_b1,
                                short* __restrict__ Hh) {
  const int idx = blockIdx.x * 256 + threadIdx.x;   // over EE*BB*HH/8
  const size_t base = (size_t)idx * 8;
  float s[8];
  *(float4*)&s[0] = *(const float4*)&EncP[base];
  *(float4*)&s[4] = *(const float4*)&EncP[base + 4];
  {
    const float* p = EncP + (size_t)(EE * BB * HH) + base;
    float q[8];
    *(float4*)&q[0] = *(const float4*)p;
    *(float4*)&q[4] = *(const float4*)(p + 4);
#pragma unroll
    for (int j = 0; j < 8; ++j) s[j] += q[j];
  }
  const int e = (int)(base / (BB * HH));
  const int col = (int)(base % HH);
  short h8[8];
#pragma unroll
  for (int j = 0; j < 8; ++j) {
    const float v = fmaxf(s[j] + enc_b1[e * HH + col + j], 0.f);
    h8[j] = (short)f2bf_u(v);
  }
  *(bf16x8*)&Hh[base] = *(bf16x8*)h8;
}

// ---------------------------------------------------------------------------
// MAIN dec3 + fused loss, 256x256 tile, 8 waves, BK=32 swizzled 4-buffer
// depth-3 pipeline with COUNTED vmcnt (r16 depth-2 proven; deepened).
// Tail peel: c<=13 vmcnt(8), c=14 vmcnt(4), c=15 vmcnt(0).
// ---------------------------------------------------------------------------
__global__ __launch_bounds__(512, 2) void gemm_loss256_k(
    const short* __restrict__ Ahg, const short* __restrict__ Bhg,
    const float* __restrict__ bias, const short* __restrict__ xfh,
    float* __restrict__ partials) {
  __shared__ short sA[4][256 * 32];
  __shared__ short sB[4][256 * 32];
  __shared__ float red[256][4];
  // XCD-aware remap: 1024 blocks, each XCD gets one expert's contiguous grid.
  int lin = blockIdx.x + 32 * (blockIdx.y + 4 * blockIdx.z);
  lin = (lin & 7) * 128 + (lin >> 3);
  const int bx = lin & 31, by = (lin >> 5) & 3, e = lin >> 7;
  const int m0 = by * 256, n0 = bx * 256;
  const int Kb = HH * 2;
  const short* Ae = Ahg + ((size_t)e * BB + m0) * HH;
  const short* Be = Bhg + ((size_t)e * DD + n0) * HH;

  const int t = threadIdx.x, w = t >> 6, lane = t & 63;
  const int wm = w >> 2, wn = w & 3;
  const int lo32 = (w * 16 + (lane >> 2)) * Kb +
                   (((lane & 3) ^ ((lane >> 3) & 3)) << 4);
  const int r16 = lane & 15, g = lane >> 4;
  const int c32 = (g ^ ((r16 >> 1) & 3)) << 4;
  const int abase = (wm * 128 + r16) * 64 + c32;
  const int bbase = (wn * 64 + r16) * 64 + c32;

  f32x4 acc[8][4];
#pragma unroll
  for (int m = 0; m < 8; ++m)
#pragma unroll
    for (int n = 0; n < 4; ++n) acc[m][n] = (f32x4){0.f, 0.f, 0.f, 0.f};

  // Prologue: stages 0,1,2 in flight (4 loads each per wave).
  stage32<256, 8>(Ae, Kb, sA[0], w, lo32);
  stage32<256, 8>(Be, Kb, sB[0], w, lo32);
  stage32<256, 8>(Ae + 32, Kb, sA[1], w, lo32);
  stage32<256, 8>(Be + 32, Kb, sB[1], w, lo32);
  stage32<256, 8>(Ae + 64, Kb, sA[2], w, lo32);
  stage32<256, 8>(Be + 64, Kb, sB[2], w, lo32);
#pragma unroll
  for (int c = 0; c < 14; ++c) {
    fence_cnt8();                 // stage c done; c+1, c+2 may fly
    if (c + 3 < 16) {
      stage32<256, 8>(Ae + (c + 3) * 32, Kb, sA[(c + 3) % 4], w, lo32);
      stage32<256, 8>(Be + (c + 3) * 32, Kb, sB[(c + 3) % 4], w, lo32);
    }
    mma32<8, 4>((const char*)sA[c % 4], (const char*)sB[c % 4], abase, bbase, acc);
  }
  fence_cnt4();                   // stage 14 done; 15 may fly
  mma32<8, 4>((const char*)sA[14 % 4], (const char*)sB[14 % 4], abase, bbase, acc);
  pipe_fence();                   // stage 15 drained
  mma32<8, 4>((const char*)sA[15 % 4], (const char*)sB[15 % 4], abase, bbase, acc);

  float rs[8][4];
#pragma unroll
  for (int m = 0; m < 8; ++m)
#pragma unroll
    for (int r = 0; r < 4; ++r) rs[m][r] = 0.f;
#pragma unroll
  for (int n = 0; n < 4; ++n) {
    const int cn = n0 + wn * 64 + n * 16 + r16;
    const float bv = bias[(size_t)e * DD + cn];
#pragma unroll
    for (int m = 0; m < 8; ++m)
#pragma unroll
      for (int r = 0; r < 4; ++r) {
        const int row = m0 + wm * 128 + m * 16 + g * 4 + r;
        const float d = acc[m][n][r] + bv - bf2f(xfh[(size_t)row * DD + cn]);
        rs[m][r] = fmaf(d, d, rs[m][r]);
      }
  }
#pragma unroll
  for (int off = 1; off < 16; off <<= 1)
#pragma unroll
    for (int m = 0; m < 8; ++m)
#pragma unroll
      for (int r = 0; r < 4; ++r) rs[m][r] += __shfl_xor(rs[m][r], off);
  if (r16 == 0) {
#pragma unroll
    for (int m = 0; m < 8; ++m)
#pragma unroll
      for (int r = 0; r < 4; ++r) red[wm * 128 + m * 16 + g * 4 + r][wn] = rs[m][r];
  }
  __syncthreads();
  if (t < 256)
    partials[((size_t)e * BB + m0 + t) * 32 + bx] =
        red[t][0] + red[t][1] + red[t][2] + red[t][3];
}

// ---------------------------------------------------------------------------
// dec3 + fused loss, 128x128 tile, NPASS=3 only (re-resolve path, f32 x).
// ---------------------------------------------------------------------------
template <int NPASS>
__global__ __launch_bounds__(256, 2) void gemm_loss_k(
    const short* __restrict__ Ahg, const short* __restrict__ Alg,
    const short* __restrict__ Bhg, const short* __restrict__ Blg,
    const float* __restrict__ bias, const float* __restrict__ xf,
    const int* __restrict__ rows, const int* __restrict__ cntPtr,
    float* __restrict__ partials, int K) {
  constexpr int NF = 4;
  __shared__ short sA[2 * 128 * 64];
  __shared__ short sB[2 * 128 * 64];
  __shared__ float red[128][2];
  const int e = blockIdx.z;
  const int m0 = blockIdx.y * 128, n0 = blockIdx.x * 128;
  int cntA = BB;
  if (cntPtr) {
    cntA = cntPtr[0];
    if (m0 >= ((cntA + 127) & ~127)) return;
  }
  const short* Ae = Ahg + ((size_t)e * BB + m0) * K;
  const short* Ale = Alg + ((size_t)e * BB + m0) * K;
  const short* Be = Bhg + ((size_t)e * DD + n0) * K;
  const short* Ble = Blg + ((size_t)e * DD + n0) * K;

  const int t = threadIdx.x, w = t >> 6, lane = t & 63;
  const int wm = w >> 1, wn = w & 1;
  const int Kb = K * 2;
  const int laneoff = (w * 8 + (lane >> 3)) * Kb + (((lane & 7) ^ ((lane >> 3) & 7)) << 4);
  const int r16 = lane & 15, g = lane >> 4;
  const int c0 = ((g ^ (r16 & 7)) << 4);
  const int abase = (wm * 64 + r16) * 128 + c0;
  const int bbase = (wn * 64 + r16) * 128 + c0;

  f32x4 acc[4][NF];
#pragma unroll
  for (int m = 0; m < 4; ++m)
#pragma unroll
    for (int n = 0; n < NF; ++n) acc[m][n] = (f32x4){0.f, 0.f, 0.f, 0.f};

  for (int k0 = 0; k0 < K; k0 += 64) {
    stageG<128, 4>(Ae + k0, Kb, sA, w, laneoff);
    stageG<128, 4>(Ale + k0, Kb, sA + 128 * 64, w, laneoff);
    stageG<128, 4>(Be + k0, Kb, sB, w, laneoff);
    stageG<128, 4>(Ble + k0, Kb, sB + 128 * 64, w, laneoff);
    __syncthreads();
    mma_chunk<NPASS, NF>((const char*)sA, (const char*)(sA + 128 * 64),
                         (const char*)sB, (const char*)(sB + 128 * 64), abase, bbase, acc);
    __syncthreads();
  }

  float rs[4][4];
#pragma unroll
  for (int m = 0; m < 4; ++m)
#pragma unroll
    for (int r = 0; r < 4; ++r) rs[m][r] = 0.f;
#pragma unroll
  for (int n = 0; n < NF; ++n) {
    const int cn = n0 + wn * 64 + n * 16 + r16;
    const float bv = bias[(size_t)e * DD + cn];
#pragma unroll
    for (int m = 0; m < 4; ++m)
#pragma unroll
      for (int r = 0; r < 4; ++r) {
        const int lrow = m0 + wm * 64 + m * 16 + g * 4 + r;
        const int xr = rows ? (lrow < cntA ? rows[lrow] : 0) : lrow;
        const float d = acc[m][n][r] + bv - xf[(size_t)xr * DD + cn];
        rs[m][r] = fmaf(d, d, rs[m][r]);
      }
  }
#pragma unroll
  for (int off = 1; off < 16; off <<= 1)
#pragma unroll
    for (int m = 0; m < 4; ++m)
#pragma unroll
      for (int r = 0; r < 4; ++r) rs[m][r] += __shfl_xor(rs[m][r], off);
  if (r16 == 0) {
#pragma unroll
    for (int m = 0; m < 4; ++m)
#pragma unroll
      for (int r = 0; r < 4; ++r) red[wm * 64 + m * 16 + g * 4 + r][wn] = rs[m][r];
  }
  __syncthreads();
  if (t < 128)
    partials[((size_t)e * BB + m0 + t) * 64 + blockIdx.x] = red[t][0] + red[t][1];
}

// ---------------------------------------------------------------------------
// Final xhat recompute, 256x256 tile, 8 waves, gathered A, BK=32 swizzled
// 4-buffer depth-3 COUNTED pipeline (same transform as gemm_loss256_k).
// ---------------------------------------------------------------------------
__global__ __launch_bounds__(512, 2) void gather_out256_k(
    const short* __restrict__ Ahg, const short* __restrict__ Bhg,
    const float* __restrict__ bias, const int* __restrict__ counts,
    const int* __restrict__ lists, float* __restrict__ out) {
  __shared__ short sA[4][256 * 32];
  __shared__ short sB[4][256 * 32];
  __shared__ int rows_s[256];
  const int e = blockIdx.z;
  const int cnt = counts[e];
  const int m0 = blockIdx.y * 256;
  if (m0 >= cnt) return;
  const int n0 = blockIdx.x * 256;
  const int Kb = HH * 2;
  const short* Ae = Ahg + (size_t)e * BB * HH;
  const short* Be = Bhg + ((size_t)e * DD + n0) * HH;

  const int t = threadIdx.x, w = t >> 6, lane = t & 63;
  const int wm = w >> 2, wn = w & 3;
  const int soff = ((lane & 3) ^ ((lane >> 3) & 3)) << 4;  // swizzled slot
  const int lo32 = (w * 16 + (lane >> 2)) * Kb + soff;
  const int r16 = lane & 15, g = lane >> 4;
  const int c32 = (g ^ ((r16 >> 1) & 3)) << 4;
  const int abase = (wm * 128 + r16) * 64 + c32;
  const int bbase = (wn * 64 + r16) * 64 + c32;

  if (t < 256) rows_s[t] = (m0 + t < cnt) ? lists[e * BB + m0 + t] : -1;
  __syncthreads();
  const int r1 = w * 16 + (lane >> 2), r2 = r1 + 128;
  int g1 = rows_s[r1]; g1 = g1 < 0 ? 0 : g1;
  int g2 = rows_s[r2]; g2 = g2 < 0 ? 0 : g2;

  f32x4 acc[8][4];
#pragma unroll
  for (int m = 0; m < 8; ++m)
#pragma unroll
    for (int n = 0; n < 4; ++n) acc[m][n] = (f32x4){0.f, 0.f, 0.f, 0.f};

  auto STAGE_A = [&](int ke, short* dst) {
    gload16((const char*)Ae + (size_t)g1 * Kb + (size_t)ke * 2 + soff,
            (char*)dst + w * 1024);
    gload16((const char*)Ae + (size_t)g2 * Kb + (size_t)ke * 2 + soff,
            (char*)dst + 8192 + w * 1024);
  };

  // Prologue: stages 0,1,2 in flight (4 loads each per wave).
  STAGE_A(0, sA[0]);
  stage32<256, 8>(Be, Kb, sB[0], w, lo32);
  STAGE_A(32, sA[1]);
  stage32<256, 8>(Be + 32, Kb, sB[1], w, lo32);
  STAGE_A(64, sA[2]);
  stage32<256, 8>(Be + 64, Kb, sB[2], w, lo32);
#pragma unroll
  for (int c = 0; c < 14; ++c) {
    fence_cnt8();
    if (c + 3 < 16) {
      STAGE_A((c + 3) * 32, sA[(c + 3) % 4]);
      stage32<256, 8>(Be + (c + 3) * 32, Kb, sB[(c + 3) % 4], w, lo32);
    }
    mma32<8, 4>((const char*)sA[c % 4], (const char*)sB[c % 4], abase, bbase, acc);
  }
  fence_cnt4();
  mma32<8, 4>((const char*)sA[14 % 4], (const char*)sB[14 % 4], abase, bbase, acc);
  pipe_fence();
  mma32<8, 4>((const char*)sA[15 % 4], (const char*)sB[15 % 4], abase, bbase, acc);

#pragma unroll
  for (int n = 0; n < 4; ++n) {
    const int cn = n0 + wn * 64 + n * 16 + r16;
    const float bv = bias[(size_t)e * DD + cn];
#pragma unroll
    for (int m = 0; m < 8; ++m)
#pragma unroll
      for (int r = 0; r < 4; ++r) {
        const int rout = rows_s[wm * 128 + m * 16 + g * 4 + r];
        if (rout >= 0) out[(size_t)rout * DD + cn] = acc[m][n][r] + bv;
      }
  }
}

// ---------------------------------------------------------------------------
// Split-K enc1 re-resolve (3-pass): rows 0..255 via 2 m-blocks, KS=8 K-chunks
// of 1024. Grid (8n x 8ks, 2m, 8e) = 1024 blocks. A is EXPERT-SHARED.
// ---------------------------------------------------------------------------
__global__ __launch_bounds__(256, 2) void enc1_pksplit_k(
    const short* __restrict__ Ahg, const short* __restrict__ Alg,
    const short* __restrict__ Bhg, const short* __restrict__ Blg,
    const int* __restrict__ cntPtr, float* __restrict__ PAf) {
  __shared__ short sA[2 * 128 * 64];
  __shared__ short sB[2 * 64 * 64];
  const int cnt = cntPtr[0];
  if (cnt == 0) return;
  const int m0 = blockIdx.y * 128;
  if (m0 >= ((cnt + 127) & ~127)) return;
  const int e = blockIdx.z;
  const int n0 = (blockIdx.x & 7) * 64;
  const int ks = blockIdx.x >> 3;
  const int Kb = DD * 2;
  const short* Ae = Ahg + (size_t)m0 * DD;    // expert-shared gathered rows
  const short* Ale = Alg + (size_t)m0 * DD;
  const short* Be = Bhg + ((size_t)e * HH + n0) * DD;
  const short* Ble = Blg + ((size_t)e * HH + n0) * DD;

  const int t = threadIdx.x, w = t >> 6, lane = t & 63;
  const int wm = w >> 1, wn = w & 1;
  const int laneoff = (w * 8 + (lane >> 3)) * Kb + (((lane & 7) ^ ((lane >> 3) & 7)) << 4);
  const int r16 = lane & 15, g = lane >> 4;
  const int c0 = ((g ^ (r16 & 7)) << 4);
  const int abase = (wm * 64 + r16) * 128 + c0;
  const int bbase = (wn * 32 + r16) * 128 + c0;

  f32x4 acc[4][2];
#pragma unroll
  for (int m = 0; m < 4; ++m)
#pragma unroll
    for (int n = 0; n < 2; ++n) acc[m][n] = (f32x4){0.f, 0.f, 0.f, 0.f};

  const int kbeg = ks * 1024, kend = kbeg + 1024;
  for (int k0 = kbeg; k0 < kend; k0 += 64) {
    stageG<128, 4>(Ae + k0, Kb, sA, w, laneoff);
    stageG<128, 4>(Ale + k0, Kb, sA + 128 * 64, w, laneoff);
    stageG<64, 4>(Be + k0, Kb, sB, w, laneoff);
    stageG<64, 4>(Ble + k0, Kb, sB + 64 * 64, w, laneoff);
    __syncthreads();
    mma_chunk<3, 2>((const char*)sA, (const char*)(sA + 128 * 64),
                    (const char*)sB, (const char*)(sB + 64 * 64), abase, bbase, acc);
    __syncthreads();
  }

#pragma unroll
  for (int n = 0; n < 2; ++n) {
    const int cn = n0 + wn * 32 + n * 16 + r16;
#pragma unroll
    for (int m = 0; m < 4; ++m)
#pragma unroll
      for (int r = 0; r < 4; ++r) {
        const int row = m0 + wm * 64 + m * 16 + g * 4 + r;
        PAf[(((size_t)ks * EE + e) * 256 + row) * HH + cn] = acc[m][n][r];
      }
  }
}

// Sum KS=8 partials + bias + relu + split -> PAh/PAl. Flat grid (512 blocks),
// 8 elem/thread, cnt-gated.
__global__ void fuse_enc1_k(const float* __restrict__ PAf,
                            const float* __restrict__ enc_b1,
                            const int* __restrict__ ambc,
                            short* __restrict__ PAh, short* __restrict__ PAl) {
  const int cnt = ambc[0];
  if (cnt == 0) return;
  const int cntPad = (cnt + 127) & ~127;
  const int idx = blockIdx.x * 256 + threadIdx.x;   // over EE*256*HH/8
  const size_t base = (size_t)idx * 8;
  const int e = (int)(base / (256 * HH));
  const int rem = (int)(base % (256 * HH));
  const int row = rem / HH;
  if (row >= cntPad) return;
  const int col = rem % HH;
  const size_t src = ((size_t)e * 256 + row) * HH + col;
  float s[8];
  *(float4*)&s[0] = *(const float4*)&PAf[src];
  *(float4*)&s[4] = *(const float4*)&PAf[src + 4];
#pragma unroll
  for (int ks = 1; ks < 8; ++ks) {
    const float* p = PAf + (size_t)ks * (EE * 256 * HH) + src;
    float q[8];
    *(float4*)&q[0] = *(const float4*)p;
    *(float4*)&q[4] = *(const float4*)(p + 4);
#pragma unroll
    for (int j = 0; j < 8; ++j) s[j] += q[j];
  }
  short h8[8], l8[8];
#pragma unroll
  for (int j = 0; j < 8; ++j) {
    const float v = fmaxf(s[j] + enc_b1[e * HH + col + j], 0.f);
    split2(v, h8[j], l8[j]);
  }
  const size_t o = ((size_t)e * BB + row) * HH + col;
  *(bf16x8*)&PAh[o] = *(bf16x8*)h8;
  *(bf16x8*)&PAl[o] = *(bf16x8*)l8;
}

// ---------------------------------------------------------------------------
// Prep / small kernels
// ---------------------------------------------------------------------------
__global__ void init_k(int* ambc) { ambc[0] = 0; }

__global__ void split_x_k(const float* __restrict__ x, short* __restrict__ Xh) {
  const int i = (blockIdx.x * 256 + threadIdx.x) * 8;
  float v[8];
  *(float4*)&v[0] = ld4(x + i);
  *(float4*)&v[4] = ld4(x + i + 4);
  short h[8];
#pragma unroll
  for (int j = 0; j < 8; ++j) h[j] = (short)f2bf_u(v[j]);
  *(bf16x8*)&Xh[i] = *(bf16x8*)h;
}

__global__ void biascat_k(const float* __restrict__ mu_b, const float* __restrict__ lv_b,
                          float* __restrict__ mlvB) {
  const int e = blockIdx.x, t = threadIdx.x;
  mlvB[e * 256 + t] = t < 128 ? mu_b[e * 128 + t] : lv_b[e * 128 + t - 128];
}

// W [E][K][N] f32 -> Th/Tl [E][rowsPerE][K] bf16 hi/lo (transposed, K-major)
__global__ __launch_bounds__(256) void trans_split_k(
    const float* __restrict__ W, short* __restrict__ Th, short* __restrict__ Tl,
    int K, int N, int rowOff, int rowsPerE) {
  const int e = blockIdx.z;
  const int k0 = blockIdx.x * 64, n0 = blockIdx.y * 64;
  __shared__ float tile[64][65];
  const int t = threadIdx.x;
  const int tr = t >> 2, tc = (t & 3) * 16;
  const float* Wp = W + ((size_t)e * K + k0 + tr) * N + n0 + tc;
#pragma unroll
  for (int c = 0; c < 4; ++c) {
    float4 v = *(const float4*)(Wp + c * 4);
    tile[tr][tc + c * 4 + 0] = v.x;
    tile[tr][tc + c * 4 + 1] = v.y;
    tile[tr][tc + c * 4 + 2] = v.z;
    tile[tr][tc + c * 4 + 3] = v.w;
  }
  __syncthreads();
  short h8[16], l8[16];
#pragma unroll
  for (int j = 0; j < 16; ++j) split2(tile[tc + j][tr], h8[j], l8[j]);
  const size_t o = ((size_t)e * rowsPerE + rowOff + n0 + tr) * K + k0 + tc;
  *(bf16x8*)&Th[o] = *(bf16x8*)&h8[0];
  *(bf16x8*)&Th[o + 8] = *(bf16x8*)&h8[8];
  *(bf16x8*)&Tl[o] = *(bf16x8*)&l8[0];
  *(bf16x8*)&Tl[o + 8] = *(bf16x8*)&l8[8];
}

__global__ void z_k(const float* __restrict__ mlv, const float* __restrict__ eps,
                    short* __restrict__ Zh) {
  const int t = blockIdx.x * 256 + threadIdx.x;  // E*B*Z
  const int eb = t >> 7, z = t & 127;
  const float mu = mlv[(size_t)eb * 256 + z], lv = mlv[(size_t)eb * 256 + 128 + z];
  Zh[t] = (short)f2bf_u(fmaf(expf(0.5f * lv), eps[t], mu));
}

__global__ void zP_k(const float* __restrict__ mlvP, const float* __restrict__ eps,
                     const int* __restrict__ ambc, const int* __restrict__ amb,
                     short* __restrict__ ZgH, short* __restrict__ ZgL) {
  const int t = blockIdx.x * 256 + threadIdx.x;  // E*1024*Z
  const int eb = t >> 7, z = t & 127;
  const int e = eb >> 10, i = eb & 1023;
  const int cntA = ambc[0];
  if (i >= ((cntA + 127) & ~127)) return;
  const int b = (i < cntA) ? amb[i] : 0;
  const float mu = mlvP[(size_t)eb * 256 + z], lv = mlvP[(size_t)eb * 256 + 128 + z];
  const float v = fmaf(expf(0.5f * lv), eps[((size_t)e * BB + b) * ZZ + z], mu);
  short h, l;
  split2(v, h, l);
  ZgH[t] = h;
  ZgL[t] = l;
}

__global__ void gather_x_k(const float* __restrict__ x, const int* __restrict__ ambc,
                           const int* __restrict__ amb, short* __restrict__ XgH,
                           short* __restrict__ XgL) {
  const int i = blockIdx.x;
  const int cntA = ambc[0];
  if (i >= ((cntA + 127) & ~127)) return;
  const int b = (i < cntA) ? amb[i] : 0;
  const float* xr = x + (size_t)b * DD;
  short* oh = XgH + (size_t)i * DD;
  short* ol = XgL + (size_t)i * DD;
  for (int j = threadIdx.x * 8; j < DD; j += 256 * 8) {
    float v[8];
    *(float4*)&v[0] = ld4(xr + j);
    *(float4*)&v[4] = ld4(xr + j + 4);
    short h[8], l[8];
#pragma unroll
    for (int q = 0; q < 8; ++q) split2(v[q], h[q], l[q]);
    *(bf16x8*)&oh[j] = *(bf16x8*)h;
    *(bf16x8*)&ol[j] = *(bf16x8*)l;
  }
}

__global__ void loss_reduce_k(const float* __restrict__ part, float* __restrict__ loss,
                              const int* __restrict__ cntPtr, int NBLK) {
  const int id = blockIdx.x * 256 + threadIdx.x;  // E*1024
  if (cntPtr) {
    if ((id & 1023) >= ((cntPtr[0] + 127) & ~127)) return;
  }
  const float* p = part + (size_t)id * NBLK;
  float s = 0.f;
  for (int j = 0; j < NBLK; ++j) s += p[j];
  loss[id] = s;
}

__global__ void argmin_flag_k(const float* __restrict__ loss, int* __restrict__ idx,
                              float* __restrict__ out_ix, int* __restrict__ ambc,
                              int* __restrict__ amb) {
  const int b = blockIdx.x * 256 + threadIdx.x;
  float best = loss[b], sec = 3.0e38f;
  int bi = 0;
#pragma unroll
  for (int e = 1; e < EE; ++e) {
    const float v = loss[e * BB + b];
    if (v < best) { sec = best; best = v; bi = e; }
    else if (v < sec) sec = v;
  }
  idx[b] = bi;
  out_ix[b] = (float)bi;
  // flag samples whose bf16-chain loss gap could be ambiguous (~17 sigma).
  if (sec - best < 10.0f + 0.001f * best) {
    int p = atomicAdd(ambc, 1);
    amb[p] = b;
  }
}

__global__ void fix_idx_k(const float* __restrict__ lossP, const int* __restrict__ ambc,
                          const int* __restrict__ amb, int* __restrict__ idx,
                          float* __restrict__ out_ix) {
  const int i = blockIdx.x * 256 + threadIdx.x;
  if (i >= ambc[0]) return;
  const int b = amb[i];
  float best = lossP[i];
  int bi = 0;
#pragma unroll
  for (int e = 1; e < EE; ++e) {
    const float v = lossP[e * 1024 + i];
    if (v < best) { best = v; bi = e; }
  }
  idx[b] = bi;
  out_ix[b] = (float)bi;
}

__global__ void select_k(const float* __restrict__ mlv, const int* __restrict__ idx,
                         float* __restrict__ out_mu, float* __restrict__ out_lv) {
  const int t = blockIdx.x * 256 + threadIdx.x;  // B*Z
  const int b = t >> 7, z = t & 127;
  const int e = idx[b];
  out_mu[t] = mlv[((size_t)(e * BB + b)) * 256 + z];
  out_lv[t] = mlv[((size_t)(e * BB + b)) * 256 + 128 + z];
}

__global__ void compact_k(const int* __restrict__ idx, int* __restrict__ counts,
                          int* __restrict__ lists) {
  __shared__ int cnt[EE];
  if (threadIdx.x < EE) cnt[threadIdx.x] = 0;
  __syncthreads();
  const int b = threadIdx.x;  // blockDim = 1024
  const int e = idx[b];
  const int pos = atomicAdd(&cnt[e], 1);
  lists[e * BB + pos] = b;
  __syncthreads();
  if (threadIdx.x < EE) counts[threadIdx.x] = cnt[threadIdx.x];
}

// ---------------------------------------------------------------------------
extern "C" void kernel_launch(void* const* d_in, const int* in_sizes, int n_in,
                              void* d_out, int out_size, void* d_ws, size_t ws_size,
                              hipStream_t stream) {
  const float* x      = (const float*)d_in[0];
  const float* eps    = (const float*)d_in[1];
  const float* enc_w1 = (const float*)d_in[2];
  const float* enc_b1 = (const float*)d_in[3];
  const float* enc_w2 = (const float*)d_in[4];
  const float* enc_b2 = (const float*)d_in[5];
  const float* mu_w   = (const float*)d_in[6];
  const float* mu_b   = (const float*)d_in[7];
  const float* lv_w   = (const float*)d_in[8];
  const float* lv_b   = (const float*)d_in[9];
  const float* dec_w1 = (const float*)d_in[10];
  const float* dec_b1 = (const float*)d_in[11];
  const float* dec_w2 = (const float*)d_in[12];
  const float* dec_b2 = (const float*)d_in[13];
  const float* dec_w3 = (const float*)d_in[14];
  const float* dec_b3 = (const float*)d_in[15];

  // Workspace carve-out (~420 MB)
  char* wsb = (char*)d_ws;
  size_t off = 0;
  auto alloc = [&](size_t bytes) -> void* {
    void* p = wsb + off;
    off = (off + bytes + 511) & ~(size_t)511;
    return p;
  };
  short* Xh    = (short*)alloc(16777216);   // x bf16 (reused as XgH later)
  short* ew1Th = (short*)alloc(67108864);
  short* ew1Tl = (short*)alloc(67108864);
  short* ew2Th = (short*)alloc(4194304);
  short* ew2Tl = (short*)alloc(4194304);
  short* mlvTh = (short*)alloc(2097152);
  short* mlvTl = (short*)alloc(2097152);
  short* dw1Th = (short*)alloc(1048576);
  short* dw1Tl = (short*)alloc(1048576);
  short* dw2Th = (short*)alloc(4194304);
  short* dw2Tl = (short*)alloc(4194304);
  short* dw3Th = (short*)alloc(67108864);
  short* dw3Tl = (short*)alloc(67108864);
  short* Hh    = (short*)alloc(8388608);    // enc h1, later HD1
  short* H2h   = (short*)alloc(8388608);    // enc h2, later HD2
  float* mlv   = (float*)alloc(8388608);    // [E][B][256] mu|lv
  float* mlvB  = (float*)alloc(8192);
  short* Zh    = (short*)alloc(2097152);
  float* part  = (float*)alloc(2097152);    // main stride 32, re-resolve 64
  float* loss  = (float*)alloc(32768);
  int*   idx   = (int*)alloc(4096);
  int*   ambc  = (int*)alloc(512);
  int*   amb   = (int*)alloc(4096);
  int*   counts= (int*)alloc(512);
  int*   lists = (int*)alloc(4096);
  short* XgL   = (short*)alloc(16777216);
  short* PAh   = (short*)alloc(8388608);
  short* PAl   = (short*)alloc(8388608);
  short* PBh   = (short*)alloc(8388608);
  short* PBl   = (short*)alloc(8388608);
  float* mlvP  = (float*)alloc(8388608);
  short* ZgH   = (short*)alloc(2097152);
  short* ZgL   = (short*)alloc(2097152);
  float* lossP = (float*)alloc(32768);
  float* PAf   = (float*)alloc(33554432);   // [8 ks][8 e][256][512] f32
  short* XgH   = Xh;  // alias: Xh dead after enc1-main
  // enc1-main split-K partials (KS=2, 33.5 MB) aliased over the re-resolve
  // region (XgL..PAl, dead until gather_x which runs after fuse).
  float* EncP  = (float*)XgL;

  float* out_mu = (float*)d_out;
  float* out_lv = out_mu + (size_t)BB * ZZ;
  float* out_xh = out_lv + (size_t)BB * ZZ;
  float* out_ix = out_xh + (size_t)BB * DD;

  const dim3 blk(256);

  // Prep: conversions / transposes (run every launch; deterministic)
  init_k<<<1, 1, 0, stream>>>(ambc);
  split_x_k<<<4096, blk, 0, stream>>>(x, Xh);
  biascat_k<<<8, blk, 0, stream>>>(mu_b, lv_b, mlvB);
  trans_split_k<<<dim3(128, 8, 8), blk, 0, stream>>>(enc_w1, ew1Th, ew1Tl, 8192, 512, 0, 512);
  trans_split_k<<<dim3(8, 8, 8), blk, 0, stream>>>(enc_w2, ew2Th, ew2Tl, 512, 512, 0, 512);
  trans_split_k<<<dim3(8, 2, 8), blk, 0, stream>>>(mu_w, mlvTh, mlvTl, 512, 128, 0, 256);
  trans_split_k<<<dim3(8, 2, 8), blk, 0, stream>>>(lv_w, mlvTh, mlvTl, 512, 128, 128, 256);
  trans_split_k<<<dim3(2, 8, 8), blk, 0, stream>>>(dec_w1, dw1Th, dw1Tl, 128, 512, 0, 512);
  trans_split_k<<<dim3(8, 8, 8), blk, 0, stream>>>(dec_w2, dw2Th, dw2Tl, 512, 512, 0, 512);
  trans_split_k<<<dim3(8, 128, 8), blk, 0, stream>>>(dec_w3, dw3Th, dw3Tl, 512, 8192, 0, 8192);

  // Main chain: 1-pass bf16. enc1 via split-K (KS=2, XCD-remapped, 128x128
  // single-buffer) + fuse.
  enc1_mainsplit_k<<<dim3(512), blk, 0, stream>>>(Xh, ew1Th, EncP);
  fuse_enc1main_k<<<2048, blk, 0, stream>>>(EncP, enc_b1, Hh);
  gemm_k<1, 2, true, 1><<<dim3(8, 8, 8), blk, 0, stream>>>(
      Hh, nullptr, ew2Th, nullptr, enc_b2, nullptr, H2h, nullptr, 1024, 512, 512, 1, nullptr, 0);
  gemm_k<1, 2, false, 0><<<dim3(4, 8, 8), blk, 0, stream>>>(
      H2h, nullptr, mlvTh, nullptr, mlvB, mlv, nullptr, nullptr, 1024, 256, 512, 1, nullptr, 0);
  z_k<<<4096, blk, 0, stream>>>(mlv, eps, Zh);
  gemm_k<1, 2, true, 1><<<dim3(8, 8, 8), blk, 0, stream>>>(
      Zh, nullptr, dw1Th, nullptr, dec_b1, nullptr, Hh, nullptr, 1024, 512, 128, 1, nullptr, 0);
  gemm_k<1, 2, true, 1><<<dim3(8, 8, 8), blk, 0, stream>>>(
      Hh, nullptr, dw2Th, nullptr, dec_b2, nullptr, H2h, nullptr, 1024, 512, 512, 1, nullptr, 0);
  gemm_loss256_k<<<dim3(32, 4, 8), dim3(512), 0, stream>>>(
      H2h, dw3Th, dec_b3, Xh, part);
  loss_reduce_k<<<32, blk, 0, stream>>>(part, loss, nullptr, 32);
  argmin_flag_k<<<4, blk, 0, stream>>>(loss, idx, out_ix, ambc, amb);

  // Re-resolve ambiguous samples with 3-pass split-bf16 (precise, f32 x)
  gather_x_k<<<1024, blk, 0, stream>>>(x, ambc, amb, XgH, XgL);
  enc1_pksplit_k<<<dim3(64, 2, 8), blk, 0, stream>>>(
      XgH, XgL, ew1Th, ew1Tl, ambc, PAf);
  fuse_enc1_k<<<512, blk, 0, stream>>>(PAf, enc_b1, ambc, PAh, PAl);
  gemm_k<3, 2, true, 1><<<dim3(8, 8, 8), blk, 0, stream>>>(
      XgH, XgL, ew1Th, ew1Tl, enc_b1, nullptr, PAh, PAl, 1024, 512, 8192, 0, ambc, 256);
  gemm_k<3, 2, true, 1><<<dim3(8, 8, 8), blk, 0, stream>>>(
      PAh, PAl, ew2Th, ew2Tl, enc_b2, nullptr, PBh, PBl, 1024, 512, 512, 1, ambc, 0);
  gemm_k<3, 2, false, 0><<<dim3(4, 8, 8), blk, 0, stream>>>(
      PBh, PBl, mlvTh, mlvTl, mlvB, mlvP, nullptr, nullptr, 1024, 256, 512, 1, ambc, 0);
  zP_k<<<4096, blk, 0, stream>>>(mlvP, eps, ambc, amb, ZgH, ZgL);
  gemm_k<3, 2, true, 1><<<dim3(8, 8, 8), blk, 0, stream>>>(
      ZgH, ZgL, dw1Th, dw1Tl, dec_b1, nullptr, PAh, PAl, 1024, 512, 128, 1, ambc, 0);
  gemm_k<3, 2, true, 1><<<dim3(8, 8, 8), blk, 0, stream>>>(
      PAh, PAl, dw2Th, dw2Tl, dec_b2, nullptr, PBh, PBl, 1024, 512, 512, 1, ambc, 0);
  gemm_loss_k<3><<<dim3(64, 8, 8), blk, 0, stream>>>(
      PBh, PBl, dw3Th, dw3Tl, dec_b3, x, amb, ambc, part, 512);
  loss_reduce_k<<<32, blk, 0, stream>>>(part, lossP, ambc, 64);
  fix_idx_k<<<4, blk, 0, stream>>>(lossP, ambc, amb, idx, out_ix);

  // Outputs
  select_k<<<512, blk, 0, stream>>>(mlv, idx, out_mu, out_lv);
  compact_k<<<1, 1024, 0, stream>>>(idx, counts, lists);
  gather_out256_k<<<dim3(32, 4, 8), dim3(512), 0, stream>>>(
      H2h, dw3Th, dec_b3, counts, lists, out_xh);
}

// Round 19
// 619.486 us; speedup vs baseline: 1.0044x; 1.0044x over previous
//
#include <hip/hip_runtime.h>

// Problem constants
#define EE 8
#define BB 1024
#define DD 8192
#define HH 512
#define ZZ 128

typedef __attribute__((ext_vector_type(8))) short bf16x8;
typedef __attribute__((ext_vector_type(4))) float f32x4;
typedef __attribute__((address_space(1))) unsigned int u32g;
typedef __attribute__((address_space(3))) unsigned int u32l;

#define DEVI __device__ __forceinline__

DEVI float4 ld4(const float* p) { return *(const float4*)p; }

// RNE float -> bf16 bits
DEVI unsigned f2bf_u(float x) {
  unsigned u = __builtin_bit_cast(unsigned, x);
  return (u + 0x7FFFu + ((u >> 16) & 1u)) >> 16;
}
DEVI float bfu2f(unsigned h) { return __builtin_bit_cast(float, h << 16); }
DEVI float bf2f(short s) {
  return __builtin_bit_cast(float, ((unsigned)(unsigned short)s) << 16);
}
DEVI void split2(float x, short& hi, short& lo) {
  unsigned h = f2bf_u(x);
  hi = (short)h;
  lo = (short)f2bf_u(x - bfu2f(h));
}

// Direct global->LDS async copy, 16B per lane. LDS dest is wave-uniform
// base + lane*16 (linear); HW appends lane*16.
DEVI void gload16(const void* g, void* l) {
  __builtin_amdgcn_global_load_lds((const u32g*)g, (u32l*)l, 16, 0, 0);
}

// Pipeline fence: my loads drained (vmcnt 0) -> all waves here (raw barrier).
DEVI void pipe_fence() {
  __builtin_amdgcn_sched_barrier(0);
  asm volatile("s_waitcnt vmcnt(0)" ::: "memory");
  __builtin_amdgcn_s_barrier();
  __builtin_amdgcn_sched_barrier(0);
}

// Counted fence: wait until my outstanding VMEM loads <= 4 (one stage of 4
// still allowed in flight), then barrier. Used by the 3-buffer pipelines.
DEVI void fence_cnt4() {
  __builtin_amdgcn_sched_barrier(0);
  asm volatile("s_waitcnt vmcnt(4)" ::: "memory");
  __builtin_amdgcn_s_barrier();
  __builtin_amdgcn_sched_barrier(0);
}

// ---- BK=64 staging (XOR-swizzled source).
template <int ROWS, int WAVES>
DEVI void stageG(const short* src, int Kb, short* lds, int w, int laneoff) {
  const char* p = (const char*)src + laneoff;
  char* l = (char*)lds + w * 1024;
#pragma unroll
  for (int r = 0; r < ROWS / (WAVES * 8); ++r)
    gload16(p + (size_t)r * (WAVES * 8) * Kb, l + r * (WAVES * 1024));
}

// ---- BK=32 staging (slot-swizzled source; conflict-free, r12-verified).
template <int ROWS, int WAVES>
DEVI void stage32(const short* src, int Kb, short* lds, int w, int laneoff32) {
  const char* p = (const char*)src + laneoff32;
  char* l = (char*)lds + w * 1024;
#pragma unroll
  for (int r = 0; r < ROWS / (WAVES * 16); ++r)
    gload16(p + (size_t)r * (WAVES * 16) * Kb, l + r * (WAVES * 1024));
}

// One K=64 chunk (swizzled BK=64 layout).
template <int NPASS, int NF>
DEVI void mma_chunk(const char* Ah, const char* Al, const char* Bh, const char* Bl,
                    int abase, int bbase, f32x4 acc[4][NF]) {
#pragma unroll
  for (int kk = 0; kk < 2; ++kk) {
    const int kx = kk * 64;
    bf16x8 ah[4], al[4], bh[NF], bl[NF];
#pragma unroll
    for (int m = 0; m < 4; ++m) {
      ah[m] = *(const bf16x8*)(Ah + ((abase + m * 2048) ^ kx));
      if (NPASS == 3) al[m] = *(const bf16x8*)(Al + ((abase + m * 2048) ^ kx));
    }
#pragma unroll
    for (int n = 0; n < NF; ++n) {
      bh[n] = *(const bf16x8*)(Bh + ((bbase + n * 2048) ^ kx));
      if (NPASS == 3) bl[n] = *(const bf16x8*)(Bl + ((bbase + n * 2048) ^ kx));
    }
#pragma unroll
    for (int m = 0; m < 4; ++m)
#pragma unroll
      for (int n = 0; n < NF; ++n) {
        acc[m][n] = __builtin_amdgcn_mfma_f32_16x16x32_bf16(ah[m], bh[n], acc[m][n], 0, 0, 0);
        if (NPASS == 3) {
          acc[m][n] = __builtin_amdgcn_mfma_f32_16x16x32_bf16(ah[m], bl[n], acc[m][n], 0, 0, 0);
          acc[m][n] = __builtin_amdgcn_mfma_f32_16x16x32_bf16(al[m], bh[n], acc[m][n], 0, 0, 0);
        }
      }
  }
}

// One K=32 chunk, BK=32 swizzled layout.
template <int NM, int NF>
DEVI void mma32(const char* A, const char* B, int abase, int bbase,
                f32x4 acc[NM][NF]) {
  bf16x8 ah[NM], bh[NF];
#pragma unroll
  for (int m = 0; m < NM; ++m) ah[m] = *(const bf16x8*)(A + abase + m * 1024);
#pragma unroll
  for (int n = 0; n < NF; ++n) bh[n] = *(const bf16x8*)(B + bbase + n * 1024);
#pragma unroll
  for (int m = 0; m < NM; ++m)
#pragma unroll
    for (int n = 0; n < NF; ++n)
      acc[m][n] = __builtin_amdgcn_mfma_f32_16x16x32_bf16(ah[m], bh[n], acc[m][n], 0, 0, 0);
}

// ---------------------------------------------------------------------------
// 4-wave GEMM (128 x NF*32 tile), single-buffer 2-barrier loop.
// ---------------------------------------------------------------------------
template <int NPASS, int NF, bool RELU, int OUT>
__global__ __launch_bounds__(256, (NPASS == 3 ? 2 : 3)) void gemm_k(
    const short* __restrict__ Ahg, const short* __restrict__ Alg,
    const short* __restrict__ Bhg, const short* __restrict__ Blg,
    const float* __restrict__ bias,
    float* __restrict__ Yf, short* __restrict__ Yh, short* __restrict__ Yl,
    int M, int N, int K, int APE, const int* __restrict__ cntPtr, int mSkip) {
  constexpr int BN = NF * 32;
  __shared__ short sA[(NPASS == 3 ? 2 : 1) * 128 * 64];
  __shared__ short sB[(NPASS == 3 ? 2 : 1) * BN * 64];
  const int e = blockIdx.z;
  const int m0 = blockIdx.y * 128, n0 = blockIdx.x * BN;
  if (m0 < mSkip) return;
  if (cntPtr) {
    if (m0 >= ((cntPtr[0] + 127) & ~127)) return;
  }
  const size_t eA = APE ? (size_t)e * M * K : 0;
  const short* Ae = Ahg + eA + (size_t)m0 * K;
  const short* Ale = (NPASS == 3) ? (Alg + eA + (size_t)m0 * K) : nullptr;
  const short* Be = Bhg + ((size_t)e * N + n0) * K;
  const short* Ble = (NPASS == 3) ? (Blg + ((size_t)e * N + n0) * K) : nullptr;

  const int t = threadIdx.x, w = t >> 6, lane = t & 63;
  const int wm = w >> 1, wn = w & 1;
  const int Kb = K * 2;
  const int laneoff = (w * 8 + (lane >> 3)) * Kb + (((lane & 7) ^ ((lane >> 3) & 7)) << 4);
  const int r16 = lane & 15, g = lane >> 4;
  const int c0 = ((g ^ (r16 & 7)) << 4);
  const int abase = (wm * 64 + r16) * 128 + c0;
  const int bbase = (wn * (NF * 16) + r16) * 128 + c0;

  f32x4 acc[4][NF];
#pragma unroll
  for (int m = 0; m < 4; ++m)
#pragma unroll
    for (int n = 0; n < NF; ++n) acc[m][n] = (f32x4){0.f, 0.f, 0.f, 0.f};

  for (int k0 = 0; k0 < K; k0 += 64) {
    stageG<128, 4>(Ae + k0, Kb, sA, w, laneoff);
    if (NPASS == 3) stageG<128, 4>(Ale + k0, Kb, sA + 128 * 64, w, laneoff);
    stageG<BN, 4>(Be + k0, Kb, sB, w, laneoff);
    if (NPASS == 3) stageG<BN, 4>(Ble + k0, Kb, sB + BN * 64, w, laneoff);
    __syncthreads();
    mma_chunk<NPASS, NF>((const char*)sA, (const char*)(sA + 128 * 64),
                         (const char*)sB, (const char*)(sB + BN * 64), abase, bbase, acc);
    __syncthreads();
  }

  const int col0 = n0 + wn * (NF * 16);
#pragma unroll
  for (int n = 0; n < NF; ++n) {
    const int cn = col0 + n * 16 + r16;
    const float bv = bias[(size_t)e * N + cn];
#pragma unroll
    for (int m = 0; m < 4; ++m)
#pragma unroll
      for (int r = 0; r < 4; ++r) {
        const int row = m0 + wm * 64 + m * 16 + g * 4 + r;
        float v = acc[m][n][r] + bv;
        if (RELU) v = fmaxf(v, 0.f);
        const size_t o = ((size_t)e * M + row) * N + cn;
        if (OUT == 0) {
          Yf[o] = v;
        } else {
          unsigned hb = f2bf_u(v);
          Yh[o] = (short)hb;
          if (NPASS == 3) Yl[o] = (short)f2bf_u(v - bfu2f(hb));
        }
      }
  }
}

// ---------------------------------------------------------------------------
// MAIN enc1 split-K, KS=2, BK=64 single-buffer, 128x128 tile (r13-proven).
// Grid 512 blocks: e = raw&7 (XCD owns one expert's B panel), m innermost.
// ---------------------------------------------------------------------------
__global__ __launch_bounds__(256, 4) void enc1_mainsplit_k(
    const short* __restrict__ Xhg, const short* __restrict__ Bhg,
    float* __restrict__ EncP) {
  __shared__ short sA[128 * 64];
  __shared__ short sB[128 * 64];
  const int raw = blockIdx.x;
  const int e = raw & 7;
  const int q = raw >> 3;          // [0,64)
  const int m0 = (q & 7) * 128;    // m innermost: B-slice shared by 8 adjacent
  const int ks = (q >> 3) & 1;
  const int n0 = (q >> 4) * 128;   // 4 n-blocks of 128
  const int Kb = DD * 2;
  const short* Ae = Xhg + (size_t)m0 * DD;
  const short* Be = Bhg + ((size_t)e * HH + n0) * DD;

  const int t = threadIdx.x, w = t >> 6, lane = t & 63;
  const int wm = w >> 1, wn = w & 1;
  const int laneoff = (w * 8 + (lane >> 3)) * Kb + (((lane & 7) ^ ((lane >> 3) & 7)) << 4);
  const int r16 = lane & 15, g = lane >> 4;
  const int c0 = ((g ^ (r16 & 7)) << 4);
  const int abase = (wm * 64 + r16) * 128 + c0;
  const int bbase = (wn * 64 + r16) * 128 + c0;

  f32x4 acc[4][4];
#pragma unroll
  for (int m = 0; m < 4; ++m)
#pragma unroll
    for (int n = 0; n < 4; ++n) acc[m][n] = (f32x4){0.f, 0.f, 0.f, 0.f};

  const int kbeg = ks * 4096, kend = kbeg + 4096;
  for (int k0 = kbeg; k0 < kend; k0 += 64) {
    stageG<128, 4>(Ae + k0, Kb, sA, w, laneoff);
    stageG<128, 4>(Be + k0, Kb, sB, w, laneoff);
    __syncthreads();
    mma_chunk<1, 4>((const char*)sA, nullptr, (const char*)sB, nullptr,
                    abase, bbase, acc);
    __syncthreads();
  }

#pragma unroll
  for (int n = 0; n < 4; ++n) {
    const int cn = n0 + wn * 64 + n * 16 + r16;
#pragma unroll
    for (int m = 0; m < 4; ++m)
#pragma unroll
      for (int r = 0; r < 4; ++r) {
        const int row = m0 + wm * 64 + m * 16 + g * 4 + r;
        EncP[(((size_t)ks * EE + e) * BB + row) * HH + cn] = acc[m][n][r];
      }
  }
}

// Sum KS=2 partials + bias + relu -> bf16 Hh. 2048 blocks x 256 thr, 8 elem/thr.
__global__ void fuse_enc1main_k(const float* __restrict__ EncP,
                                const float* __restrict__ enc_b1,
                                short* __restrict__ Hh) {
  const int idx = blockIdx.x * 256 + threadIdx.x;   // over EE*BB*HH/8
  const size_t base = (size_t)idx * 8;
  float s[8];
  *(float4*)&s[0] = *(const float4*)&EncP[base];
  *(float4*)&s[4] = *(const float4*)&EncP[base + 4];
  {
    const float* p = EncP + (size_t)(EE * BB * HH) + base;
    float q[8];
    *(float4*)&q[0] = *(const float4*)p;
    *(float4*)&q[4] = *(const float4*)(p + 4);
#pragma unroll
    for (int j = 0; j < 8; ++j) s[j] += q[j];
  }
  const int e = (int)(base / (BB * HH));
  const int col = (int)(base % HH);
  short h8[8];
#pragma unroll
  for (int j = 0; j < 8; ++j) {
    const float v = fmaxf(s[j] + enc_b1[e * HH + col + j], 0.f);
    h8[j] = (short)f2bf_u(v);
  }
  *(bf16x8*)&Hh[base] = *(bf16x8*)h8;
}

// ---------------------------------------------------------------------------
// MAIN dec3 + fused loss, 256x256 tile, 8 waves, BK=32 swizzled 3-buffer
// pipeline with COUNTED vmcnt (r16-proven: 113.8 -> 103.8 us).
// ---------------------------------------------------------------------------
__global__ __launch_bounds__(512, 2) void gemm_loss256_k(
    const short* __restrict__ Ahg, const short* __restrict__ Bhg,
    const float* __restrict__ bias, const short* __restrict__ xfh,
    float* __restrict__ partials) {
  __shared__ short sA[3][256 * 32];
  __shared__ short sB[3][256 * 32];
  __shared__ float red[256][4];
  // XCD-aware remap: 1024 blocks, each XCD gets one expert's contiguous grid.
  int lin = blockIdx.x + 32 * (blockIdx.y + 4 * blockIdx.z);
  lin = (lin & 7) * 128 + (lin >> 3);
  const int bx = lin & 31, by = (lin >> 5) & 3, e = lin >> 7;
  const int m0 = by * 256, n0 = bx * 256;
  const int Kb = HH * 2;
  const short* Ae = Ahg + ((size_t)e * BB + m0) * HH;
  const short* Be = Bhg + ((size_t)e * DD + n0) * HH;

  const int t = threadIdx.x, w = t >> 6, lane = t & 63;
  const int wm = w >> 2, wn = w & 3;
  const int lo32 = (w * 16 + (lane >> 2)) * Kb +
                   (((lane & 3) ^ ((lane >> 3) & 3)) << 4);
  const int r16 = lane & 15, g = lane >> 4;
  const int c32 = (g ^ ((r16 >> 1) & 3)) << 4;
  const int abase = (wm * 128 + r16) * 64 + c32;
  const int bbase = (wn * 64 + r16) * 64 + c32;

  f32x4 acc[8][4];
#pragma unroll
  for (int m = 0; m < 8; ++m)
#pragma unroll
    for (int n = 0; n < 4; ++n) acc[m][n] = (f32x4){0.f, 0.f, 0.f, 0.f};

  // Prologue: stages 0 and 1 in flight (4 loads each per wave).
  stage32<256, 8>(Ae, Kb, sA[0], w, lo32);
  stage32<256, 8>(Be, Kb, sB[0], w, lo32);
  stage32<256, 8>(Ae + 32, Kb, sA[1], w, lo32);
  stage32<256, 8>(Be + 32, Kb, sB[1], w, lo32);
#pragma unroll
  for (int c = 0; c < 15; ++c) {
    fence_cnt4();                 // my stage-c loads done; stage-c+1 may fly
    if (c + 2 < 16) {
      stage32<256, 8>(Ae + (c + 2) * 32, Kb, sA[(c + 2) % 3], w, lo32);
      stage32<256, 8>(Be + (c + 2) * 32, Kb, sB[(c + 2) % 3], w, lo32);
    }
    mma32<8, 4>((const char*)sA[c % 3], (const char*)sB[c % 3], abase, bbase, acc);
  }
  pipe_fence();
  mma32<8, 4>((const char*)sA[15 % 3], (const char*)sB[15 % 3], abase, bbase, acc);

  float rs[8][4];
#pragma unroll
  for (int m = 0; m < 8; ++m)
#pragma unroll
    for (int r = 0; r < 4; ++r) rs[m][r] = 0.f;
#pragma unroll
  for (int n = 0; n < 4; ++n) {
    const int cn = n0 + wn * 64 + n * 16 + r16;
    const float bv = bias[(size_t)e * DD + cn];
#pragma unroll
    for (int m = 0; m < 8; ++m)
#pragma unroll
      for (int r = 0; r < 4; ++r) {
        const int row = m0 + wm * 128 + m * 16 + g * 4 + r;
        const float d = acc[m][n][r] + bv - bf2f(xfh[(size_t)row * DD + cn]);
        rs[m][r] = fmaf(d, d, rs[m][r]);
      }
  }
#pragma unroll
  for (int off = 1; off < 16; off <<= 1)
#pragma unroll
    for (int m = 0; m < 8; ++m)
#pragma unroll
      for (int r = 0; r < 4; ++r) rs[m][r] += __shfl_xor(rs[m][r], off);
  if (r16 == 0) {
#pragma unroll
    for (int m = 0; m < 8; ++m)
#pragma unroll
      for (int r = 0; r < 4; ++r) red[wm * 128 + m * 16 + g * 4 + r][wn] = rs[m][r];
  }
  __syncthreads();
  if (t < 256)
    partials[((size_t)e * BB + m0 + t) * 32 + bx] =
        red[t][0] + red[t][1] + red[t][2] + red[t][3];
}

// ---------------------------------------------------------------------------
// dec3 + fused loss, 128x128 tile, NPASS=3 only (re-resolve path, f32 x).
// ---------------------------------------------------------------------------
template <int NPASS>
__global__ __launch_bounds__(256, 2) void gemm_loss_k(
    const short* __restrict__ Ahg, const short* __restrict__ Alg,
    const short* __restrict__ Bhg, const short* __restrict__ Blg,
    const float* __restrict__ bias, const float* __restrict__ xf,
    const int* __restrict__ rows, const int* __restrict__ cntPtr,
    float* __restrict__ partials, int K) {
  constexpr int NF = 4;
  __shared__ short sA[2 * 128 * 64];
  __shared__ short sB[2 * 128 * 64];
  __shared__ float red[128][2];
  const int e = blockIdx.z;
  const int m0 = blockIdx.y * 128, n0 = blockIdx.x * 128;
  int cntA = BB;
  if (cntPtr) {
    cntA = cntPtr[0];
    if (m0 >= ((cntA + 127) & ~127)) return;
  }
  const short* Ae = Ahg + ((size_t)e * BB + m0) * K;
  const short* Ale = Alg + ((size_t)e * BB + m0) * K;
  const short* Be = Bhg + ((size_t)e * DD + n0) * K;
  const short* Ble = Blg + ((size_t)e * DD + n0) * K;

  const int t = threadIdx.x, w = t >> 6, lane = t & 63;
  const int wm = w >> 1, wn = w & 1;
  const int Kb = K * 2;
  const int laneoff = (w * 8 + (lane >> 3)) * Kb + (((lane & 7) ^ ((lane >> 3) & 7)) << 4);
  const int r16 = lane & 15, g = lane >> 4;
  const int c0 = ((g ^ (r16 & 7)) << 4);
  const int abase = (wm * 64 + r16) * 128 + c0;
  const int bbase = (wn * 64 + r16) * 128 + c0;

  f32x4 acc[4][NF];
#pragma unroll
  for (int m = 0; m < 4; ++m)
#pragma unroll
    for (int n = 0; n < NF; ++n) acc[m][n] = (f32x4){0.f, 0.f, 0.f, 0.f};

  for (int k0 = 0; k0 < K; k0 += 64) {
    stageG<128, 4>(Ae + k0, Kb, sA, w, laneoff);
    stageG<128, 4>(Ale + k0, Kb, sA + 128 * 64, w, laneoff);
    stageG<128, 4>(Be + k0, Kb, sB, w, laneoff);
    stageG<128, 4>(Ble + k0, Kb, sB + 128 * 64, w, laneoff);
    __syncthreads();
    mma_chunk<NPASS, NF>((const char*)sA, (const char*)(sA + 128 * 64),
                         (const char*)sB, (const char*)(sB + 128 * 64), abase, bbase, acc);
    __syncthreads();
  }

  float rs[4][4];
#pragma unroll
  for (int m = 0; m < 4; ++m)
#pragma unroll
    for (int r = 0; r < 4; ++r) rs[m][r] = 0.f;
#pragma unroll
  for (int n = 0; n < NF; ++n) {
    const int cn = n0 + wn * 64 + n * 16 + r16;
    const float bv = bias[(size_t)e * DD + cn];
#pragma unroll
    for (int m = 0; m < 4; ++m)
#pragma unroll
      for (int r = 0; r < 4; ++r) {
        const int lrow = m0 + wm * 64 + m * 16 + g * 4 + r;
        const int xr = rows ? (lrow < cntA ? rows[lrow] : 0) : lrow;
        const float d = acc[m][n][r] + bv - xf[(size_t)xr * DD + cn];
        rs[m][r] = fmaf(d, d, rs[m][r]);
      }
  }
#pragma unroll
  for (int off = 1; off < 16; off <<= 1)
#pragma unroll
    for (int m = 0; m < 4; ++m)
#pragma unroll
      for (int r = 0; r < 4; ++r) rs[m][r] += __shfl_xor(rs[m][r], off);
  if (r16 == 0) {
#pragma unroll
    for (int m = 0; m < 4; ++m)
#pragma unroll
      for (int r = 0; r < 4; ++r) red[wm * 64 + m * 16 + g * 4 + r][wn] = rs[m][r];
  }
  __syncthreads();
  if (t < 128)
    partials[((size_t)e * BB + m0 + t) * 64 + blockIdx.x] = red[t][0] + red[t][1];
}

// ---------------------------------------------------------------------------
// Final xhat recompute, 256x256 tile, 8 waves, gathered A, BK=32 swizzled
// 3-buffer COUNTED pipeline (same transform as gemm_loss256_k, r16-proven;
// 4 gloads/stage/wave here too: STAGE_A=2 + stage32 B=2 -> vmcnt(4) valid).
// ---------------------------------------------------------------------------
__global__ __launch_bounds__(512, 2) void gather_out256_k(
    const short* __restrict__ Ahg, const short* __restrict__ Bhg,
    const float* __restrict__ bias, const int* __restrict__ counts,
    const int* __restrict__ lists, float* __restrict__ out) {
  __shared__ short sA[3][256 * 32];
  __shared__ short sB[3][256 * 32];
  __shared__ int rows_s[256];
  const int e = blockIdx.z;
  const int cnt = counts[e];
  const int m0 = blockIdx.y * 256;
  if (m0 >= cnt) return;
  const int n0 = blockIdx.x * 256;
  const int Kb = HH * 2;
  const short* Ae = Ahg + (size_t)e * BB * HH;
  const short* Be = Bhg + ((size_t)e * DD + n0) * HH;

  const int t = threadIdx.x, w = t >> 6, lane = t & 63;
  const int wm = w >> 2, wn = w & 3;
  const int soff = ((lane & 3) ^ ((lane >> 3) & 3)) << 4;  // swizzled slot
  const int lo32 = (w * 16 + (lane >> 2)) * Kb + soff;
  const int r16 = lane & 15, g = lane >> 4;
  const int c32 = (g ^ ((r16 >> 1) & 3)) << 4;
  const int abase = (wm * 128 + r16) * 64 + c32;
  const int bbase = (wn * 64 + r16) * 64 + c32;

  if (t < 256) rows_s[t] = (m0 + t < cnt) ? lists[e * BB + m0 + t] : -1;
  __syncthreads();
  const int r1 = w * 16 + (lane >> 2), r2 = r1 + 128;
  int g1 = rows_s[r1]; g1 = g1 < 0 ? 0 : g1;
  int g2 = rows_s[r2]; g2 = g2 < 0 ? 0 : g2;

  f32x4 acc[8][4];
#pragma unroll
  for (int m = 0; m < 8; ++m)
#pragma unroll
    for (int n = 0; n < 4; ++n) acc[m][n] = (f32x4){0.f, 0.f, 0.f, 0.f};

  auto STAGE_A = [&](int ke, short* dst) {
    gload16((const char*)Ae + (size_t)g1 * Kb + (size_t)ke * 2 + soff,
            (char*)dst + w * 1024);
    gload16((const char*)Ae + (size_t)g2 * Kb + (size_t)ke * 2 + soff,
            (char*)dst + 8192 + w * 1024);
  };

  // Prologue: stages 0 and 1 in flight (4 loads each per wave).
  STAGE_A(0, sA[0]);
  stage32<256, 8>(Be, Kb, sB[0], w, lo32);
  STAGE_A(32, sA[1]);
  stage32<256, 8>(Be + 32, Kb, sB[1], w, lo32);
#pragma unroll
  for (int c = 0; c < 15; ++c) {
    fence_cnt4();
    if (c + 2 < 16) {
      STAGE_A((c + 2) * 32, sA[(c + 2) % 3]);
      stage32<256, 8>(Be + (c + 2) * 32, Kb, sB[(c + 2) % 3], w, lo32);
    }
    mma32<8, 4>((const char*)sA[c % 3], (const char*)sB[c % 3], abase, bbase, acc);
  }
  pipe_fence();
  mma32<8, 4>((const char*)sA[15 % 3], (const char*)sB[15 % 3], abase, bbase, acc);

#pragma unroll
  for (int n = 0; n < 4; ++n) {
    const int cn = n0 + wn * 64 + n * 16 + r16;
    const float bv = bias[(size_t)e * DD + cn];
#pragma unroll
    for (int m = 0; m < 8; ++m)
#pragma unroll
      for (int r = 0; r < 4; ++r) {
        const int rout = rows_s[wm * 128 + m * 16 + g * 4 + r];
        if (rout >= 0) out[(size_t)rout * DD + cn] = acc[m][n][r] + bv;
      }
  }
}

// ---------------------------------------------------------------------------
// Split-K enc1 re-resolve (3-pass): rows 0..255 via 2 m-blocks, KS=8 K-chunks
// of 1024. Grid (8n x 8ks, 2m, 8e) = 1024 blocks. A is EXPERT-SHARED.
// ---------------------------------------------------------------------------
__global__ __launch_bounds__(256, 2) void enc1_pksplit_k(
    const short* __restrict__ Ahg, const short* __restrict__ Alg,
    const short* __restrict__ Bhg, const short* __restrict__ Blg,
    const int* __restrict__ cntPtr, float* __restrict__ PAf) {
  __shared__ short sA[2 * 128 * 64];
  __shared__ short sB[2 * 64 * 64];
  const int cnt = cntPtr[0];
  if (cnt == 0) return;
  const int m0 = blockIdx.y * 128;
  if (m0 >= ((cnt + 127) & ~127)) return;
  const int e = blockIdx.z;
  const int n0 = (blockIdx.x & 7) * 64;
  const int ks = blockIdx.x >> 3;
  const int Kb = DD * 2;
  const short* Ae = Ahg + (size_t)m0 * DD;    // expert-shared gathered rows
  const short* Ale = Alg + (size_t)m0 * DD;
  const short* Be = Bhg + ((size_t)e * HH + n0) * DD;
  const short* Ble = Blg + ((size_t)e * HH + n0) * DD;

  const int t = threadIdx.x, w = t >> 6, lane = t & 63;
  const int wm = w >> 1, wn = w & 1;
  const int laneoff = (w * 8 + (lane >> 3)) * Kb + (((lane & 7) ^ ((lane >> 3) & 7)) << 4);
  const int r16 = lane & 15, g = lane >> 4;
  const int c0 = ((g ^ (r16 & 7)) << 4);
  const int abase = (wm * 64 + r16) * 128 + c0;
  const int bbase = (wn * 32 + r16) * 128 + c0;

  f32x4 acc[4][2];
#pragma unroll
  for (int m = 0; m < 4; ++m)
#pragma unroll
    for (int n = 0; n < 2; ++n) acc[m][n] = (f32x4){0.f, 0.f, 0.f, 0.f};

  const int kbeg = ks * 1024, kend = kbeg + 1024;
  for (int k0 = kbeg; k0 < kend; k0 += 64) {
    stageG<128, 4>(Ae + k0, Kb, sA, w, laneoff);
    stageG<128, 4>(Ale + k0, Kb, sA + 128 * 64, w, laneoff);
    stageG<64, 4>(Be + k0, Kb, sB, w, laneoff);
    stageG<64, 4>(Ble + k0, Kb, sB + 64 * 64, w, laneoff);
    __syncthreads();
    mma_chunk<3, 2>((const char*)sA, (const char*)(sA + 128 * 64),
                    (const char*)sB, (const char*)(sB + 64 * 64), abase, bbase, acc);
    __syncthreads();
  }

#pragma unroll
  for (int n = 0; n < 2; ++n) {
    const int cn = n0 + wn * 32 + n * 16 + r16;
#pragma unroll
    for (int m = 0; m < 4; ++m)
#pragma unroll
      for (int r = 0; r < 4; ++r) {
        const int row = m0 + wm * 64 + m * 16 + g * 4 + r;
        PAf[(((size_t)ks * EE + e) * 256 + row) * HH + cn] = acc[m][n][r];
      }
  }
}

// Sum KS=8 partials + bias + relu + split -> PAh/PAl. Flat grid (512 blocks),
// 8 elem/thread, cnt-gated.
__global__ void fuse_enc1_k(const float* __restrict__ PAf,
                            const float* __restrict__ enc_b1,
                            const int* __restrict__ ambc,
                            short* __restrict__ PAh, short* __restrict__ PAl) {
  const int cnt = ambc[0];
  if (cnt == 0) return;
  const int cntPad = (cnt + 127) & ~127;
  const int idx = blockIdx.x * 256 + threadIdx.x;   // over EE*256*HH/8
  const size_t base = (size_t)idx * 8;
  const int e = (int)(base / (256 * HH));
  const int rem = (int)(base % (256 * HH));
  const int row = rem / HH;
  if (row >= cntPad) return;
  const int col = rem % HH;
  const size_t src = ((size_t)e * 256 + row) * HH + col;
  float s[8];
  *(float4*)&s[0] = *(const float4*)&PAf[src];
  *(float4*)&s[4] = *(const float4*)&PAf[src + 4];
#pragma unroll
  for (int ks = 1; ks < 8; ++ks) {
    const float* p = PAf + (size_t)ks * (EE * 256 * HH) + src;
    float q[8];
    *(float4*)&q[0] = *(const float4*)p;
    *(float4*)&q[4] = *(const float4*)(p + 4);
#pragma unroll
    for (int j = 0; j < 8; ++j) s[j] += q[j];
  }
  short h8[8], l8[8];
#pragma unroll
  for (int j = 0; j < 8; ++j) {
    const float v = fmaxf(s[j] + enc_b1[e * HH + col + j], 0.f);
    split2(v, h8[j], l8[j]);
  }
  const size_t o = ((size_t)e * BB + row) * HH + col;
  *(bf16x8*)&PAh[o] = *(bf16x8*)h8;
  *(bf16x8*)&PAl[o] = *(bf16x8*)l8;
}

// ---------------------------------------------------------------------------
// Prep / small kernels
// ---------------------------------------------------------------------------
__global__ void init_k(int* ambc) { ambc[0] = 0; }

__global__ void split_x_k(const float* __restrict__ x, short* __restrict__ Xh) {
  const int i = (blockIdx.x * 256 + threadIdx.x) * 8;
  float v[8];
  *(float4*)&v[0] = ld4(x + i);
  *(float4*)&v[4] = ld4(x + i + 4);
  short h[8];
#pragma unroll
  for (int j = 0; j < 8; ++j) h[j] = (short)f2bf_u(v[j]);
  *(bf16x8*)&Xh[i] = *(bf16x8*)h;
}

__global__ void biascat_k(const float* __restrict__ mu_b, const float* __restrict__ lv_b,
                          float* __restrict__ mlvB) {
  const int e = blockIdx.x, t = threadIdx.x;
  mlvB[e * 256 + t] = t < 128 ? mu_b[e * 128 + t] : lv_b[e * 128 + t - 128];
}

// W [E][K][N] f32 -> Th/Tl [E][rowsPerE][K] bf16 hi/lo (transposed, K-major)
__global__ __launch_bounds__(256) void trans_split_k(
    const float* __restrict__ W, short* __restrict__ Th, short* __restrict__ Tl,
    int K, int N, int rowOff, int rowsPerE) {
  const int e = blockIdx.z;
  const int k0 = blockIdx.x * 64, n0 = blockIdx.y * 64;
  __shared__ float tile[64][65];
  const int t = threadIdx.x;
  const int tr = t >> 2, tc = (t & 3) * 16;
  const float* Wp = W + ((size_t)e * K + k0 + tr) * N + n0 + tc;
#pragma unroll
  for (int c = 0; c < 4; ++c) {
    float4 v = *(const float4*)(Wp + c * 4);
    tile[tr][tc + c * 4 + 0] = v.x;
    tile[tr][tc + c * 4 + 1] = v.y;
    tile[tr][tc + c * 4 + 2] = v.z;
    tile[tr][tc + c * 4 + 3] = v.w;
  }
  __syncthreads();
  short h8[16], l8[16];
#pragma unroll
  for (int j = 0; j < 16; ++j) split2(tile[tc + j][tr], h8[j], l8[j]);
  const size_t o = ((size_t)e * rowsPerE + rowOff + n0 + tr) * K + k0 + tc;
  *(bf16x8*)&Th[o] = *(bf16x8*)&h8[0];
  *(bf16x8*)&Th[o + 8] = *(bf16x8*)&h8[8];
  *(bf16x8*)&Tl[o] = *(bf16x8*)&l8[0];
  *(bf16x8*)&Tl[o + 8] = *(bf16x8*)&l8[8];
}

__global__ void z_k(const float* __restrict__ mlv, const float* __restrict__ eps,
                    short* __restrict__ Zh) {
  const int t = blockIdx.x * 256 + threadIdx.x;  // E*B*Z
  const int eb = t >> 7, z = t & 127;
  const float mu = mlv[(size_t)eb * 256 + z], lv = mlv[(size_t)eb * 256 + 128 + z];
  Zh[t] = (short)f2bf_u(fmaf(expf(0.5f * lv), eps[t], mu));
}

__global__ void zP_k(const float* __restrict__ mlvP, const float* __restrict__ eps,
                     const int* __restrict__ ambc, const int* __restrict__ amb,
                     short* __restrict__ ZgH, short* __restrict__ ZgL) {
  const int t = blockIdx.x * 256 + threadIdx.x;  // E*1024*Z
  const int eb = t >> 7, z = t & 127;
  const int e = eb >> 10, i = eb & 1023;
  const int cntA = ambc[0];
  if (i >= ((cntA + 127) & ~127)) return;
  const int b = (i < cntA) ? amb[i] : 0;
  const float mu = mlvP[(size_t)eb * 256 + z], lv = mlvP[(size_t)eb * 256 + 128 + z];
  const float v = fmaf(expf(0.5f * lv), eps[((size_t)e * BB + b) * ZZ + z], mu);
  short h, l;
  split2(v, h, l);
  ZgH[t] = h;
  ZgL[t] = l;
}

__global__ void gather_x_k(const float* __restrict__ x, const int* __restrict__ ambc,
                           const int* __restrict__ amb, short* __restrict__ XgH,
                           short* __restrict__ XgL) {
  const int i = blockIdx.x;
  const int cntA = ambc[0];
  if (i >= ((cntA + 127) & ~127)) return;
  const int b = (i < cntA) ? amb[i] : 0;
  const float* xr = x + (size_t)b * DD;
  short* oh = XgH + (size_t)i * DD;
  short* ol = XgL + (size_t)i * DD;
  for (int j = threadIdx.x * 8; j < DD; j += 256 * 8) {
    float v[8];
    *(float4*)&v[0] = ld4(xr + j);
    *(float4*)&v[4] = ld4(xr + j + 4);
    short h[8], l[8];
#pragma unroll
    for (int q = 0; q < 8; ++q) split2(v[q], h[q], l[q]);
    *(bf16x8*)&oh[j] = *(bf16x8*)h;
    *(bf16x8*)&ol[j] = *(bf16x8*)l;
  }
}

__global__ void loss_reduce_k(const float* __restrict__ part, float* __restrict__ loss,
                              const int* __restrict__ cntPtr, int NBLK) {
  const int id = blockIdx.x * 256 + threadIdx.x;  // E*1024
  if (cntPtr) {
    if ((id & 1023) >= ((cntPtr[0] + 127) & ~127)) return;
  }
  const float* p = part + (size_t)id * NBLK;
  float s = 0.f;
  for (int j = 0; j < NBLK; ++j) s += p[j];
  loss[id] = s;
}

__global__ void argmin_flag_k(const float* __restrict__ loss, int* __restrict__ idx,
                              float* __restrict__ out_ix, int* __restrict__ ambc,
                              int* __restrict__ amb) {
  const int b = blockIdx.x * 256 + threadIdx.x;
  float best = loss[b], sec = 3.0e38f;
  int bi = 0;
#pragma unroll
  for (int e = 1; e < EE; ++e) {
    const float v = loss[e * BB + b];
    if (v < best) { sec = best; best = v; bi = e; }
    else if (v < sec) sec = v;
  }
  idx[b] = bi;
  out_ix[b] = (float)bi;
  // flag samples whose bf16-chain loss gap could be ambiguous (~17 sigma).
  if (sec - best < 10.0f + 0.001f * best) {
    int p = atomicAdd(ambc, 1);
    amb[p] = b;
  }
}

__global__ void fix_idx_k(const float* __restrict__ lossP, const int* __restrict__ ambc,
                          const int* __restrict__ amb, int* __restrict__ idx,
                          float* __restrict__ out_ix) {
  const int i = blockIdx.x * 256 + threadIdx.x;
  if (i >= ambc[0]) return;
  const int b = amb[i];
  float best = lossP[i];
  int bi = 0;
#pragma unroll
  for (int e = 1; e < EE; ++e) {
    const float v = lossP[e * 1024 + i];
    if (v < best) { best = v; bi = e; }
  }
  idx[b] = bi;
  out_ix[b] = (float)bi;
}

__global__ void select_k(const float* __restrict__ mlv, const int* __restrict__ idx,
                         float* __restrict__ out_mu, float* __restrict__ out_lv) {
  const int t = blockIdx.x * 256 + threadIdx.x;  // B*Z
  const int b = t >> 7, z = t & 127;
  const int e = idx[b];
  out_mu[t] = mlv[((size_t)(e * BB + b)) * 256 + z];
  out_lv[t] = mlv[((size_t)(e * BB + b)) * 256 + 128 + z];
}

__global__ void compact_k(const int* __restrict__ idx, int* __restrict__ counts,
                          int* __restrict__ lists) {
  __shared__ int cnt[EE];
  if (threadIdx.x < EE) cnt[threadIdx.x] = 0;
  __syncthreads();
  const int b = threadIdx.x;  // blockDim = 1024
  const int e = idx[b];
  const int pos = atomicAdd(&cnt[e], 1);
  lists[e * BB + pos] = b;
  __syncthreads();
  if (threadIdx.x < EE) counts[threadIdx.x] = cnt[threadIdx.x];
}

// ---------------------------------------------------------------------------
extern "C" void kernel_launch(void* const* d_in, const int* in_sizes, int n_in,
                              void* d_out, int out_size, void* d_ws, size_t ws_size,
                              hipStream_t stream) {
  const float* x      = (const float*)d_in[0];
  const float* eps    = (const float*)d_in[1];
  const float* enc_w1 = (const float*)d_in[2];
  const float* enc_b1 = (const float*)d_in[3];
  const float* enc_w2 = (const float*)d_in[4];
  const float* enc_b2 = (const float*)d_in[5];
  const float* mu_w   = (const float*)d_in[6];
  const float* mu_b   = (const float*)d_in[7];
  const float* lv_w   = (const float*)d_in[8];
  const float* lv_b   = (const float*)d_in[9];
  const float* dec_w1 = (const float*)d_in[10];
  const float* dec_b1 = (const float*)d_in[11];
  const float* dec_w2 = (const float*)d_in[12];
  const float* dec_b2 = (const float*)d_in[13];
  const float* dec_w3 = (const float*)d_in[14];
  const float* dec_b3 = (const float*)d_in[15];

  // Workspace carve-out (~420 MB)
  char* wsb = (char*)d_ws;
  size_t off = 0;
  auto alloc = [&](size_t bytes) -> void* {
    void* p = wsb + off;
    off = (off + bytes + 511) & ~(size_t)511;
    return p;
  };
  short* Xh    = (short*)alloc(16777216);   // x bf16 (reused as XgH later)
  short* ew1Th = (short*)alloc(67108864);
  short* ew1Tl = (short*)alloc(67108864);
  short* ew2Th = (short*)alloc(4194304);
  short* ew2Tl = (short*)alloc(4194304);
  short* mlvTh = (short*)alloc(2097152);
  short* mlvTl = (short*)alloc(2097152);
  short* dw1Th = (short*)alloc(1048576);
  short* dw1Tl = (short*)alloc(1048576);
  short* dw2Th = (short*)alloc(4194304);
  short* dw2Tl = (short*)alloc(4194304);
  short* dw3Th = (short*)alloc(67108864);
  short* dw3Tl = (short*)alloc(67108864);
  short* Hh    = (short*)alloc(8388608);    // enc h1, later HD1
  short* H2h   = (short*)alloc(8388608);    // enc h2, later HD2
  float* mlv   = (float*)alloc(8388608);    // [E][B][256] mu|lv
  float* mlvB  = (float*)alloc(8192);
  short* Zh    = (short*)alloc(2097152);
  float* part  = (float*)alloc(2097152);    // main stride 32, re-resolve 64
  float* loss  = (float*)alloc(32768);
  int*   idx   = (int*)alloc(4096);
  int*   ambc  = (int*)alloc(512);
  int*   amb   = (int*)alloc(4096);
  int*   counts= (int*)alloc(512);
  int*   lists = (int*)alloc(4096);
  short* XgL   = (short*)alloc(16777216);
  short* PAh   = (short*)alloc(8388608);
  short* PAl   = (short*)alloc(8388608);
  short* PBh   = (short*)alloc(8388608);
  short* PBl   = (short*)alloc(8388608);
  float* mlvP  = (float*)alloc(8388608);
  short* ZgH   = (short*)alloc(2097152);
  short* ZgL   = (short*)alloc(2097152);
  float* lossP = (float*)alloc(32768);
  float* PAf   = (float*)alloc(33554432);   // [8 ks][8 e][256][512] f32
  short* XgH   = Xh;  // alias: Xh dead after enc1-main
  // enc1-main split-K partials (KS=2, 33.5 MB) aliased over the re-resolve
  // region (XgL..PAl, dead until gather_x which runs after fuse).
  float* EncP  = (float*)XgL;

  float* out_mu = (float*)d_out;
  float* out_lv = out_mu + (size_t)BB * ZZ;
  float* out_xh = out_lv + (size_t)BB * ZZ;
  float* out_ix = out_xh + (size_t)BB * DD;

  const dim3 blk(256);

  // Prep: conversions / transposes (run every launch; deterministic)
  init_k<<<1, 1, 0, stream>>>(ambc);
  split_x_k<<<4096, blk, 0, stream>>>(x, Xh);
  biascat_k<<<8, blk, 0, stream>>>(mu_b, lv_b, mlvB);
  trans_split_k<<<dim3(128, 8, 8), blk, 0, stream>>>(enc_w1, ew1Th, ew1Tl, 8192, 512, 0, 512);
  trans_split_k<<<dim3(8, 8, 8), blk, 0, stream>>>(enc_w2, ew2Th, ew2Tl, 512, 512, 0, 512);
  trans_split_k<<<dim3(8, 2, 8), blk, 0, stream>>>(mu_w, mlvTh, mlvTl, 512, 128, 0, 256);
  trans_split_k<<<dim3(8, 2, 8), blk, 0, stream>>>(lv_w, mlvTh, mlvTl, 512, 128, 128, 256);
  trans_split_k<<<dim3(2, 8, 8), blk, 0, stream>>>(dec_w1, dw1Th, dw1Tl, 128, 512, 0, 512);
  trans_split_k<<<dim3(8, 8, 8), blk, 0, stream>>>(dec_w2, dw2Th, dw2Tl, 512, 512, 0, 512);
  trans_split_k<<<dim3(8, 128, 8), blk, 0, stream>>>(dec_w3, dw3Th, dw3Tl, 512, 8192, 0, 8192);

  // Main chain: 1-pass bf16. enc1 via split-K (KS=2, XCD-remapped, 128x128
  // single-buffer) + fuse.
  enc1_mainsplit_k<<<dim3(512), blk, 0, stream>>>(Xh, ew1Th, EncP);
  fuse_enc1main_k<<<2048, blk, 0, stream>>>(EncP, enc_b1, Hh);
  gemm_k<1, 2, true, 1><<<dim3(8, 8, 8), blk, 0, stream>>>(
      Hh, nullptr, ew2Th, nullptr, enc_b2, nullptr, H2h, nullptr, 1024, 512, 512, 1, nullptr, 0);
  gemm_k<1, 2, false, 0><<<dim3(4, 8, 8), blk, 0, stream>>>(
      H2h, nullptr, mlvTh, nullptr, mlvB, mlv, nullptr, nullptr, 1024, 256, 512, 1, nullptr, 0);
  z_k<<<4096, blk, 0, stream>>>(mlv, eps, Zh);
  gemm_k<1, 2, true, 1><<<dim3(8, 8, 8), blk, 0, stream>>>(
      Zh, nullptr, dw1Th, nullptr, dec_b1, nullptr, Hh, nullptr, 1024, 512, 128, 1, nullptr, 0);
  gemm_k<1, 2, true, 1><<<dim3(8, 8, 8), blk, 0, stream>>>(
      Hh, nullptr, dw2Th, nullptr, dec_b2, nullptr, H2h, nullptr, 1024, 512, 512, 1, nullptr, 0);
  gemm_loss256_k<<<dim3(32, 4, 8), dim3(512), 0, stream>>>(
      H2h, dw3Th, dec_b3, Xh, part);
  loss_reduce_k<<<32, blk, 0, stream>>>(part, loss, nullptr, 32);
  argmin_flag_k<<<4, blk, 0, stream>>>(loss, idx, out_ix, ambc, amb);

  // Re-resolve ambiguous samples with 3-pass split-bf16 (precise, f32 x)
  gather_x_k<<<1024, blk, 0, stream>>>(x, ambc, amb, XgH, XgL);
  enc1_pksplit_k<<<dim3(64, 2, 8), blk, 0, stream>>>(
      XgH, XgL, ew1Th, ew1Tl, ambc, PAf);
  fuse_enc1_k<<<512, blk, 0, stream>>>(PAf, enc_b1, ambc, PAh, PAl);
  gemm_k<3, 2, true, 1><<<dim3(8, 8, 8), blk, 0, stream>>>(
      XgH, XgL, ew1Th, ew1Tl, enc_b1, nullptr, PAh, PAl, 1024, 512, 8192, 0, ambc, 256);
  gemm_k<3, 2, true, 1><<<dim3(8, 8, 8), blk, 0, stream>>>(
      PAh, PAl, ew2Th, ew2Tl, enc_b2, nullptr, PBh, PBl, 1024, 512, 512, 1, ambc, 0);
  gemm_k<3, 2, false, 0><<<dim3(4, 8, 8), blk, 0, stream>>>(
      PBh, PBl, mlvTh, mlvTl, mlvB, mlvP, nullptr, nullptr, 1024, 256, 512, 1, ambc, 0);
  zP_k<<<4096, blk, 0, stream>>>(mlvP, eps, ambc, amb, ZgH, ZgL);
  gemm_k<3, 2, true, 1><<<dim3(8, 8, 8), blk, 0, stream>>>(
      ZgH, ZgL, dw1Th, dw1Tl, dec_b1, nullptr, PAh, PAl, 1024, 512, 128, 1, ambc, 0);
  gemm_k<3, 2, true, 1><<<dim3(8, 8, 8), blk, 0, stream>>>(
      PAh, PAl, dw2Th, dw2Tl, dec_b2, nullptr, PBh, PBl, 1024, 512, 512, 1, ambc, 0);
  gemm_loss_k<3><<<dim3(64, 8, 8), blk, 0, stream>>>(
      PBh, PBl, dw3Th, dw3Tl, dec_b3, x, amb, ambc, part, 512);
  loss_reduce_k<<<32, blk, 0, stream>>>(part, lossP, ambc, 64);
  fix_idx_k<<<4, blk, 0, stream>>>(lossP, ambc, amb, idx, out_ix);

  // Outputs
  select_k<<<512, blk, 0, stream>>>(mlv, idx, out_mu, out_lv);
  compact_k<<<1, 1024, 0, stream>>>(idx, counts, lists);
  gather_out256_k<<<dim3(32, 4, 8), dim3(512), 0, stream>>>(
      H2h, dw3Th, dec_b3, counts, lists, out_xh);
}